// Round 7
// baseline (804.807 us; speedup 1.0000x reference)
//
#include <hip/hip_runtime.h>

#define N_NODESC 20000
#define N_EDGESC 320000
#define HC 640
#define NGRAPH 500

typedef unsigned short u16;
typedef unsigned int u32;
typedef __attribute__((ext_vector_type(8))) short bf16x8;
typedef __attribute__((ext_vector_type(4))) float f32x4;

__device__ __forceinline__ float wred_sum(float v){
  #pragma unroll
  for(int o=32;o;o>>=1) v += __shfl_xor(v,o,64);
  return v;
}
__device__ __forceinline__ float wred_max(float v){
  #pragma unroll
  for(int o=32;o;o>>=1) v = fmaxf(v,__shfl_xor(v,o,64));
  return v;
}
__device__ __forceinline__ float lrelu(float x){ return x>0.f? x:0.2f*x; }

__device__ __forceinline__ u16 f2bf(float f){
  u32 u=__float_as_uint(f);
  u32 r=u+0x7FFFu+((u>>16)&1u);
  return (u16)(r>>16);
}
__device__ __forceinline__ float bf2f(u16 s){ return __uint_as_float(((u32)s)<<16); }
__device__ __forceinline__ float bflo(u32 w){ return __uint_as_float(w<<16); }
__device__ __forceinline__ float bfhi(u32 w){ return __uint_as_float(w&0xFFFF0000u); }

__device__ __forceinline__ void gload16(const void* g, void* l){
  __builtin_amdgcn_global_load_lds((const __attribute__((address_space(1))) void*)g,
                                   (__attribute__((address_space(3))) void*)l, 16, 0, 0);
}

// ---------------- graph preprocessing (layer-invariant) ----------------

__global__ void k_count(const int* __restrict__ dst, int* __restrict__ cnt){
  int i=blockIdx.x*blockDim.x+threadIdx.x;
  if(i>=N_EDGESC) return;
  atomicAdd(&cnt[dst[i]],1);
}

__global__ void k_scan(const int* __restrict__ cnt, int* __restrict__ rptr, int* __restrict__ pos){
  __shared__ int ps[1024];
  int t=threadIdx.x;
  const int CH=20;
  int beg=t*CH, end=min(beg+CH, N_NODESC);
  int s=0;
  for(int i=beg;i<end;i++) s+=cnt[i];
  ps[t]=s; __syncthreads();
  for(int off=1;off<1024;off<<=1){
    int v=(t>=off)? ps[t-off]:0;
    __syncthreads();
    ps[t]+=v;
    __syncthreads();
  }
  int base=ps[t]-s;
  for(int i=beg;i<end;i++){ rptr[i]=base; pos[i]=base; base+=cnt[i]; }
}

__global__ void k_scatter(const int* __restrict__ dst, int* __restrict__ pos, int* __restrict__ eidx){
  int i=blockIdx.x*blockDim.x+threadIdx.x;
  if(i>=N_EDGESC) return;
  int j=atomicAdd(&pos[dst[i]],1);
  eidx[j]=i;
}

// scatter-mean of edge_attr per dst node via CSR (no atomics); one wave per node
__global__ __launch_bounds__(256) void k_loop_attr(const float* __restrict__ eattr,
    const int* __restrict__ rptr, const int* __restrict__ cnt, const int* __restrict__ eidx,
    float* __restrict__ lattr){
  int tid=threadIdx.x, lane=tid&63;
  int n=blockIdx.x*4+(tid>>6);
  if(n>=N_NODESC) return;
  int beg=rptr[n], deg=cnt[n];
  float s[10]={0,0,0,0,0,0,0,0,0,0};
  for(int off=lane; off<deg; off+=64){
    int e=eidx[beg+off];
    const float* ep=&eattr[(size_t)e*10];
    #pragma unroll
    for(int k=0;k<10;k++) s[k]+=ep[k];
  }
  float inv=1.f/fmaxf((float)deg,1.f);
  #pragma unroll
  for(int k=0;k<10;k++){
    float tot=wred_sum(s[k]);
    if(lane==0) lattr[(size_t)n*10+k]=tot*inv;
  }
}

// ---------------- conversions ----------------

__global__ void k_conv_x(const float* __restrict__ x, u16* __restrict__ hi, u16* __restrict__ lo){
  int idx=blockIdx.x*blockDim.x+threadIdx.x;
  if(idx>=N_NODESC*64) return;
  int n=idx>>6, kk=idx&63;
  float v = kk<43 ? x[n*43+kk] : 0.f;
  u16 h=f2bf(v);
  hi[idx]=h; lo[idx]=f2bf(v-bf2f(h));
}

__global__ void k_conv_w(const float* __restrict__ W, u16* __restrict__ hi, u16* __restrict__ lo,
                         int KL, int KP){
  int idx=blockIdx.x*blockDim.x+threadIdx.x;
  if(idx>=HC*KP) return;
  int kk=idx/HC;
  int n=idx-kk*HC;
  float v = kk<KL ? W[(size_t)kk*HC+n] : 0.f;
  u16 h=f2bf(v);
  hi[(size_t)n*KP+kk]=h;
  lo[(size_t)n*KP+kk]=f2bf(v-bf2f(h));
}

// ---------------- per-layer kernels ----------------

__global__ void k_ve(const float* __restrict__ We, const float* __restrict__ aedge,
                     float* __restrict__ ve){
  int t=threadIdx.x;
  if(t>=50) return;
  int k=t/5, h=t%5;
  float s=0.f;
  for(int c=0;c<128;c++) s += We[k*HC + h*128 + c]*aedge[h*128+c];
  ve[k*5+h]=s;
}

// ael[n][h] = lattr[n,:] . ve[:,h]
__global__ void k_ael(const float* __restrict__ lattr, const float* __restrict__ ve,
                      float* __restrict__ ael){
  int idx=blockIdx.x*blockDim.x+threadIdx.x;
  if(idx>=N_NODESC*5) return;
  int n=idx/5, h=idx-5*n;
  float s=0.f;
  #pragma unroll
  for(int k=0;k<10;k++) s+=lattr[(size_t)n*10+k]*ve[k*5+h];
  ael[idx]=s;
}

// Fused GEMM + nodeatt: writes permuted bf16 hb + per-head al/ar.
// A-hi/lo staged in LDS (32 KiB); B fragments read directly from global (L2-hot).
// 128x128 tile, BK=64, 4 waves each 64x64, XCD-bijective swizzle.
__global__ __launch_bounds__(256,4) void k_gemm_fused(
    const u16* __restrict__ Ahi, const u16* __restrict__ Alo,
    const u16* __restrict__ Bhi, const u16* __restrict__ Blo,
    const float* __restrict__ asrc, const float* __restrict__ adst,
    u16* __restrict__ hb, float* __restrict__ al, float* __restrict__ ar,
    int M, int KP, int nblk){
  __shared__ u16 lA[2][8192];
  int tid=threadIdx.x;
  int lane=tid&63;
  int w=tid>>6;
  int l15=lane&15, lg=lane>>4;
  // XCD-bijective swizzle: contiguous wg chunks per XCD
  int orig=blockIdx.x;
  int q=nblk>>3, r=nblk&7;
  int xcd=orig&7, off=orig>>3;
  int wg=(xcd<r? xcd*(q+1) : r*(q+1)+(xcd-r)*q)+off;
  int by=wg/5, bx=wg-5*by;
  int row0=by*128, col0=bx*128;
  int wr=w>>1, wc=w&1;

  f32x4 zero = {0.f,0.f,0.f,0.f};
  f32x4 acc[4][4];
  #pragma unroll
  for(int i=0;i<4;i++)
    #pragma unroll
    for(int j=0;j<4;j++) acc[i][j]=zero;

  for(int k0=0;k0<KP;k0+=64){
    // stage A-hi/A-lo (16 sub-blocks of 16 rows x 32 k each)
    #pragma unroll
    for(int c=0;c<4;c++){
      int sb=w+4*c;          // fm = sb>>1, ks = sb&1
      int fm=sb>>1, ks=sb&1;
      int acol=k0+ks*32+lg*8;
      size_t aoff=(size_t)(row0+fm*16+l15)*KP + acol;
      gload16(Ahi+aoff, &lA[0][sb*512]);
      gload16(Alo+aoff, &lA[1][sb*512]);
    }
    __syncthreads();
    #pragma unroll
    for(int ks=0;ks<2;ks++){
      bf16x8 ah[4], alv[4], bh[4], bl[4];
      #pragma unroll
      for(int i=0;i<4;i++){
        int sbA=(wr*4+i)*2+ks;
        ah[i] =*(const bf16x8*)&lA[0][sbA*512+lane*8];
        alv[i]=*(const bf16x8*)&lA[1][sbA*512+lane*8];
        // B direct from global (L2): col = col0 + (wc*4+i)*16 + l15, k = k0+ks*32+lg*8
        size_t boff=(size_t)(col0+(wc*4+i)*16+l15)*KP + k0+ks*32+lg*8;
        bh[i]=*(const bf16x8*)&Bhi[boff];
        bl[i]=*(const bf16x8*)&Blo[boff];
      }
      #pragma unroll
      for(int i=0;i<4;i++)
        #pragma unroll
        for(int j=0;j<4;j++){
          acc[i][j]=__builtin_amdgcn_mfma_f32_16x16x32_bf16(ah[i], bh[j],acc[i][j],0,0,0);
          acc[i][j]=__builtin_amdgcn_mfma_f32_16x16x32_bf16(alv[i],bh[j],acc[i][j],0,0,0);
          acc[i][j]=__builtin_amdgcn_mfma_f32_16x16x32_bf16(ah[i], bl[j],acc[i][j],0,0,0);
        }
    }
    __syncthreads();
  }

  // ---- epilogue: hb (permuted bf16) + al/ar for head bx ----
  float asv[4], adv[4];
  #pragma unroll
  for(int j=0;j<4;j++){
    int c=col0+wc*64+j*16+l15;
    asv[j]=asrc[c]; adv[j]=adst[c];
  }
  // hb[n*640 + (c&63)*10 + (c>>6)] ; c&63 = j*16+l15 ; c>>6 = bx*2+wc
  #pragma unroll
  for(int i=0;i<4;i++){
    #pragma unroll
    for(int j=0;j<4;j++){
      #pragma unroll
      for(int rr=0;rr<4;rr++){
        int row=row0+wr*64+i*16+lg*4+rr;
        if(row<M) hb[(size_t)row*HC + (j*16+l15)*10 + bx*2+wc]=f2bf(acc[i][j][rr]);
      }
    }
  }
  // per-row partial dot over this wave's 64 cols, reduce across l15
  float* redAl=(float*)&lA[0][0];       // 128*2 floats
  float* redAr=redAl+256;
  #pragma unroll
  for(int i=0;i<4;i++){
    #pragma unroll
    for(int rr=0;rr<4;rr++){
      float sa=0.f, sd=0.f;
      #pragma unroll
      for(int j=0;j<4;j++){ sa+=acc[i][j][rr]*asv[j]; sd+=acc[i][j][rr]*adv[j]; }
      #pragma unroll
      for(int o=1;o<16;o<<=1){ sa+=__shfl_xor(sa,o,64); sd+=__shfl_xor(sd,o,64); }
      if(l15==0){
        int lr=wr*64+i*16+lg*4+rr;
        redAl[lr*2+wc]=sa; redAr[lr*2+wc]=sd;
      }
    }
  }
  __syncthreads();
  if(tid<128){
    int row=row0+tid;
    if(row<M){
      al[(size_t)row*5+bx]=redAl[tid*2]+redAl[tid*2+1];
      ar[(size_t)row*5+bx]=redAr[tid*2]+redAr[tid*2+1];
    }
  }
}

__global__ void k_ae(const float* __restrict__ eattr, const float* __restrict__ ve,
                     float* __restrict__ ae){
  __shared__ float ves[50];
  if(threadIdx.x<50) ves[threadIdx.x]=ve[threadIdx.x];
  __syncthreads();
  int i=blockIdx.x*blockDim.x+threadIdx.x;
  if(i>=N_EDGESC) return;
  float ev[10];
  #pragma unroll
  for(int k=0;k<10;k++) ev[k]=eattr[i*10+k];
  #pragma unroll
  for(int hh=0;hh<5;hh++){
    float s=0.f;
    #pragma unroll
    for(int k=0;k<10;k++) s+=ev[k]*ves[k*5+hh];
    ae[(size_t)i*5+hh]=s;
  }
}

// fused segment-softmax + aggregation; one wave per node. Gathers bf16 hb rows.
// WBF: write bf16 hi/lo (next layer GEMM input). else: write f32 out.
template<bool RELU, bool WBF>
__global__ __launch_bounds__(256) void k_agg(const u16* __restrict__ hb, const int* __restrict__ src,
    const int* __restrict__ rptr, const int* __restrict__ cnt, const int* __restrict__ eidx,
    const float* __restrict__ al, const float* __restrict__ ar, const float* __restrict__ ael,
    const float* __restrict__ ae, const float* __restrict__ bias,
    float* __restrict__ out, u16* __restrict__ ohi, u16* __restrict__ olo){
  int tid=threadIdx.x, lane=tid&63;
  int n=blockIdx.x*4+(tid>>6);
  if(n>=N_NODESC) return;
  float arn[5], m[5], den[5], acc[10];
  #pragma unroll
  for(int hh=0;hh<5;hh++) arn[hh]=ar[n*5+hh];
  #pragma unroll
  for(int hh=0;hh<5;hh++){
    m[hh]=lrelu(al[n*5+hh]+arn[hh]+ael[n*5+hh]);
    den[hh]=1.f;
  }
  {
    const u32* sp=(const u32*)(hb+(size_t)n*HC+lane*10);
    #pragma unroll
    for(int j2=0;j2<5;j2++){
      u32 wv=sp[j2];
      acc[2*j2]  =bflo(wv);
      acc[2*j2+1]=bfhi(wv);
    }
  }
  int beg=rptr[n], deg=cnt[n];
  for(int off0=0; off0<deg; off0+=64){
    int c=min(64,deg-off0);
    bool valid = lane<c;
    int s=0; float p[5];
    #pragma unroll
    for(int hh=0;hh<5;hh++) p[hh]=-1e30f;
    if(valid){
      int e=eidx[beg+off0+lane];
      s=src[e];
      #pragma unroll
      for(int hh=0;hh<5;hh++) p[hh]=lrelu(al[s*5+hh]+arn[hh]+ae[(size_t)e*5+hh]);
    }
    float sc[5];
    #pragma unroll
    for(int hh=0;hh<5;hh++){
      float cm=wred_max(p[hh]);
      float nm=fmaxf(m[hh],cm);
      sc[hh]=__expf(m[hh]-nm);
      den[hh]*=sc[hh];
      float pv = valid? __expf(p[hh]-nm) : 0.f;
      p[hh]=pv;
      den[hh]+=wred_sum(pv);
      m[hh]=nm;
    }
    #pragma unroll
    for(int k=0;k<10;k++) acc[k]*=sc[k>>1];
    for(int j=0;j<c;j++){
      int sj=__shfl(s,j,64);
      float pj[5];
      #pragma unroll
      for(int hh=0;hh<5;hh++) pj[hh]=__shfl(p[hh],j,64);
      const u32* hr=(const u32*)(hb+(size_t)sj*HC+lane*10);
      #pragma unroll
      for(int j2=0;j2<5;j2++){
        u32 wv=hr[j2];
        acc[2*j2]  +=pj[j2]*bflo(wv);
        acc[2*j2+1]+=pj[j2]*bfhi(wv);
      }
    }
  }
  #pragma unroll
  for(int k=0;k<10;k++){
    int ccol=lane+64*k;
    float v=acc[k]/(den[k>>1]+1e-16f)+bias[ccol];
    if(RELU) v=fmaxf(v,0.f);
    if(WBF){
      u16 h=f2bf(v);
      ohi[(size_t)n*HC+ccol]=h;
      olo[(size_t)n*HC+ccol]=f2bf(v-bf2f(h));
    }else{
      out[(size_t)n*HC+ccol]=v;
    }
  }
}

// ---------------- pooling + head ----------------

__global__ __launch_bounds__(256) void k_pool(const float* __restrict__ h, const float* __restrict__ wlin,
    const int* __restrict__ batch, float* __restrict__ ysum, float* __restrict__ cntg){
  int tid=threadIdx.x, lane=tid&63;
  int n=blockIdx.x*4+(tid>>6);
  if(n>=N_NODESC) return;
  float s=0.f;
  #pragma unroll
  for(int k=0;k<10;k++){ int c=lane+64*k; s+=h[(size_t)n*HC+c]*wlin[c]; }
  s=wred_sum(s);
  if(lane==0){
    int g=batch[n];
    atomicAdd(&ysum[g],s);
    atomicAdd(&cntg[g],1.f);
  }
}

__global__ void k_final(const float* __restrict__ ysum, const float* __restrict__ cntg,
                        const float* __restrict__ blin, float* __restrict__ out){
  int g=blockIdx.x*blockDim.x+threadIdx.x;
  if(g>=NGRAPH) return;
  out[g]=ysum[g]/fmaxf(cntg[g],1.f)+blin[0];
}

// ---------------- launch ----------------

extern "C" void kernel_launch(void* const* d_in, const int* in_sizes, int n_in,
                              void* d_out, int out_size, void* d_ws, size_t ws_size,
                              hipStream_t stream){
  const float* x     = (const float*)d_in[0];
  const float* eattr = (const float*)d_in[1];
  const float* W[3]    ={(const float*)d_in[2],(const float*)d_in[8],(const float*)d_in[14]};
  const float* We[3]   ={(const float*)d_in[3],(const float*)d_in[9],(const float*)d_in[15]};
  const float* asrc[3] ={(const float*)d_in[4],(const float*)d_in[10],(const float*)d_in[16]};
  const float* adst[3] ={(const float*)d_in[5],(const float*)d_in[11],(const float*)d_in[17]};
  const float* aedge[3]={(const float*)d_in[6],(const float*)d_in[12],(const float*)d_in[18]};
  const float* bias[3] ={(const float*)d_in[7],(const float*)d_in[13],(const float*)d_in[19]};
  const float* Wlin  = (const float*)d_in[20];
  const float* blin  = (const float*)d_in[21];
  const int* eind    = (const int*)d_in[22];
  const int* srcp    = eind;
  const int* dstp    = eind + N_EDGESC;
  const int* batch   = (const int*)d_in[23];
  float* out = (float*)d_out;

  char* ws=(char*)d_ws;
  size_t o=0;
  auto alloc=[&](size_t bytes)->void*{ void* p=ws+o; o=(o+bytes+255)&~(size_t)255; return p; };
  u16* hb   =(u16*)alloc((size_t)N_NODESC*HC*2);           // permuted bf16 h
  float* aggf =(float*)alloc((size_t)N_NODESC*HC*4);       // final layer f32 out
  u16* Ahi =(u16*)alloc((size_t)N_NODESC*HC*2);            // agg bf16 out (next GEMM A)
  u16* Alo =(u16*)alloc((size_t)N_NODESC*HC*2);
  u16* Axhi=(u16*)alloc((size_t)N_NODESC*64*2);            // converted x (KP=64)
  u16* Axlo=(u16*)alloc((size_t)N_NODESC*64*2);
  u16* Bthi=(u16*)alloc((size_t)HC*HC*2);                  // transposed weights
  u16* Btlo=(u16*)alloc((size_t)HC*HC*2);
  float* al   =(float*)alloc((size_t)N_NODESC*5*4);
  float* ar   =(float*)alloc((size_t)N_NODESC*5*4);
  float* ael  =(float*)alloc((size_t)N_NODESC*5*4);
  float* ae   =(float*)alloc((size_t)N_EDGESC*5*4);
  float* lattr=(float*)alloc((size_t)N_NODESC*10*4);
  float* ve   =(float*)alloc(64*4);
  float* ysum =(float*)alloc(512*4);
  float* cntg =(float*)alloc(512*4);
  int* cntI   =(int*)alloc((size_t)N_NODESC*4);
  int* rptr   =(int*)alloc((size_t)N_NODESC*4);
  int* pos    =(int*)alloc((size_t)N_NODESC*4);
  int* eidx   =(int*)alloc((size_t)N_EDGESC*4);

  hipMemsetAsync(cntI,0,(size_t)N_NODESC*4,stream);
  hipMemsetAsync(ysum,0,512*4,stream);
  hipMemsetAsync(cntg,0,512*4,stream);

  k_count<<<(N_EDGESC+255)/256,256,0,stream>>>(dstp,cntI);
  k_scan<<<1,1024,0,stream>>>(cntI,rptr,pos);
  k_scatter<<<(N_EDGESC+255)/256,256,0,stream>>>(dstp,pos,eidx);
  k_loop_attr<<<(N_NODESC+3)/4,256,0,stream>>>(eattr,rptr,cntI,eidx,lattr);
  k_conv_x<<<(N_NODESC*64+255)/256,256,0,stream>>>(x,Axhi,Axlo);

  const int NBLK=5*((N_NODESC+127)/128);
  for(int L=0;L<3;L++){
    int KL = (L==0)? 43 : HC;
    int KP = (L==0)? 64 : HC;
    const u16* Ah = (L==0)? Axhi : Ahi;
    const u16* Al = (L==0)? Axlo : Alo;
    k_ve<<<1,64,0,stream>>>(We[L],aedge[L],ve);
    k_conv_w<<<(HC*KP+255)/256,256,0,stream>>>(W[L],Bthi,Btlo,KL,KP);
    k_gemm_fused<<<NBLK,256,0,stream>>>(Ah,Al,Bthi,Btlo,asrc[L],adst[L],hb,al,ar,N_NODESC,KP,NBLK);
    k_ael<<<(N_NODESC*5+255)/256,256,0,stream>>>(lattr,ve,ael);
    k_ae<<<(N_EDGESC+255)/256,256,0,stream>>>(eattr,ve,ae);
    if(L<2)
      k_agg<true ,true ><<<(N_NODESC+3)/4,256,0,stream>>>(hb,srcp,rptr,cntI,eidx,al,ar,ael,ae,bias[L],aggf,Ahi,Alo);
    else
      k_agg<false,false><<<(N_NODESC+3)/4,256,0,stream>>>(hb,srcp,rptr,cntI,eidx,al,ar,ael,ae,bias[L],aggf,Ahi,Alo);
  }
  k_pool<<<(N_NODESC+3)/4,256,0,stream>>>(aggf,Wlin,batch,ysum,cntg);
  k_final<<<2,256,0,stream>>>(ysum,cntg,blin,out);
}

// Round 8
// 607.354 us; speedup vs baseline: 1.3251x; 1.3251x over previous
//
#include <hip/hip_runtime.h>

#define N_NODESC 20000
#define N_EDGESC 320000
#define HC 640
#define NGRAPH 500

typedef unsigned short u16;
typedef unsigned int u32;
typedef __attribute__((ext_vector_type(8))) short bf16x8;
typedef __attribute__((ext_vector_type(4))) float f32x4;

__device__ __forceinline__ float wred_sum(float v){
  #pragma unroll
  for(int o=32;o;o>>=1) v += __shfl_xor(v,o,64);
  return v;
}
__device__ __forceinline__ float wred_max(float v){
  #pragma unroll
  for(int o=32;o;o>>=1) v = fmaxf(v,__shfl_xor(v,o,64));
  return v;
}
__device__ __forceinline__ float lrelu(float x){ return x>0.f? x:0.2f*x; }

__device__ __forceinline__ u16 f2bf(float f){
  u32 u=__float_as_uint(f);
  u32 r=u+0x7FFFu+((u>>16)&1u);
  return (u16)(r>>16);
}
__device__ __forceinline__ float bf2f(u16 s){ return __uint_as_float(((u32)s)<<16); }
__device__ __forceinline__ float bflo(u32 w){ return __uint_as_float(w<<16); }
__device__ __forceinline__ float bfhi(u32 w){ return __uint_as_float(w&0xFFFF0000u); }

__device__ __forceinline__ void gload16(const void* g, void* l){
  __builtin_amdgcn_global_load_lds((const __attribute__((address_space(1))) void*)g,
                                   (__attribute__((address_space(3))) void*)l, 16, 0, 0);
}

// ---------------- graph preprocessing (layer-invariant) ----------------

__global__ void k_count(const int* __restrict__ dst, int* __restrict__ cnt){
  int i=blockIdx.x*blockDim.x+threadIdx.x;
  if(i>=N_EDGESC) return;
  atomicAdd(&cnt[dst[i]],1);
}

__global__ void k_scan(const int* __restrict__ cnt, int* __restrict__ rptr, int* __restrict__ pos){
  __shared__ int ps[1024];
  int t=threadIdx.x;
  const int CH=20;
  int beg=t*CH, end=min(beg+CH, N_NODESC);
  int s=0;
  for(int i=beg;i<end;i++) s+=cnt[i];
  ps[t]=s; __syncthreads();
  for(int off=1;off<1024;off<<=1){
    int v=(t>=off)? ps[t-off]:0;
    __syncthreads();
    ps[t]+=v;
    __syncthreads();
  }
  int base=ps[t]-s;
  for(int i=beg;i<end;i++){ rptr[i]=base; pos[i]=base; base+=cnt[i]; }
}

__global__ void k_scatter(const int* __restrict__ dst, int* __restrict__ pos, int* __restrict__ eidx){
  int i=blockIdx.x*blockDim.x+threadIdx.x;
  if(i>=N_EDGESC) return;
  int j=atomicAdd(&pos[dst[i]],1);
  eidx[j]=i;
}

// scatter-mean of edge_attr per dst node via CSR (no atomics); one wave per node
__global__ __launch_bounds__(256) void k_loop_attr(const float* __restrict__ eattr,
    const int* __restrict__ rptr, const int* __restrict__ cnt, const int* __restrict__ eidx,
    float* __restrict__ lattr){
  int tid=threadIdx.x, lane=tid&63;
  int n=blockIdx.x*4+(tid>>6);
  if(n>=N_NODESC) return;
  int beg=rptr[n], deg=cnt[n];
  float s[10]={0,0,0,0,0,0,0,0,0,0};
  for(int off=lane; off<deg; off+=64){
    int e=eidx[beg+off];
    const float* ep=&eattr[(size_t)e*10];
    #pragma unroll
    for(int k=0;k<10;k++) s[k]+=ep[k];
  }
  float inv=1.f/fmaxf((float)deg,1.f);
  #pragma unroll
  for(int k=0;k<10;k++){
    float tot=wred_sum(s[k]);
    if(lane==0) lattr[(size_t)n*10+k]=tot*inv;
  }
}

// ---------------- conversions ----------------

__global__ void k_conv_x(const float* __restrict__ x, u16* __restrict__ hi, u16* __restrict__ lo){
  int idx=blockIdx.x*blockDim.x+threadIdx.x;
  if(idx>=N_NODESC*64) return;
  int n=idx>>6, kk=idx&63;
  float v = kk<43 ? x[n*43+kk] : 0.f;
  u16 h=f2bf(v);
  hi[idx]=h; lo[idx]=f2bf(v-bf2f(h));
}

__global__ void k_conv_w(const float* __restrict__ W, u16* __restrict__ hi, u16* __restrict__ lo,
                         int KL, int KP){
  int idx=blockIdx.x*blockDim.x+threadIdx.x;
  if(idx>=HC*KP) return;
  int kk=idx/HC;
  int n=idx-kk*HC;
  float v = kk<KL ? W[(size_t)kk*HC+n] : 0.f;
  u16 h=f2bf(v);
  hi[(size_t)n*KP+kk]=h;
  lo[(size_t)n*KP+kk]=f2bf(v-bf2f(h));
}

// ---------------- per-layer kernels ----------------

__global__ void k_ve(const float* __restrict__ We, const float* __restrict__ aedge,
                     float* __restrict__ ve){
  int t=threadIdx.x;
  if(t>=50) return;
  int k=t/5, h=t%5;
  float s=0.f;
  for(int c=0;c<128;c++) s += We[k*HC + h*128 + c]*aedge[h*128+c];
  ve[k*5+h]=s;
}

// ael[n][h] = lattr[n,:] . ve[:,h]
__global__ void k_ael(const float* __restrict__ lattr, const float* __restrict__ ve,
                      float* __restrict__ ael){
  int idx=blockIdx.x*blockDim.x+threadIdx.x;
  if(idx>=N_NODESC*5) return;
  int n=idx/5, h=idx-5*n;
  float s=0.f;
  #pragma unroll
  for(int k=0;k<10;k++) s+=lattr[(size_t)n*10+k]*ve[k*5+h];
  ael[idx]=s;
}

// Fused GEMM + nodeatt: writes permuted bf16 hb + per-head al/ar.
// NT=3: C=Ahi@Bhi+Alo@Bhi+Ahi@Blo (layer 0, x input). NT=2: C=A@Bhi+A@Blo.
// A,B staged in LDS (NT=2: 48 KiB -> 3 blocks/CU). 128x128 tile, BK=64,
// 4 waves each 64x64, XCD-bijective swizzle.
template<int NT>
__global__ __launch_bounds__(256,3) void k_gemm_fused(
    const u16* __restrict__ Ahi, const u16* __restrict__ Alo,
    const u16* __restrict__ Bhi, const u16* __restrict__ Blo,
    const float* __restrict__ asrc, const float* __restrict__ adst,
    u16* __restrict__ hb, float* __restrict__ al, float* __restrict__ ar,
    int M, int KP, int nblk){
  __shared__ u16 lA[(NT==3)?2:1][8192];
  __shared__ u16 lB[2][8192];
  int tid=threadIdx.x;
  int lane=tid&63;
  int w=tid>>6;
  int l15=lane&15, lg=lane>>4;
  // XCD-bijective swizzle: contiguous wg chunks per XCD
  int orig=blockIdx.x;
  int q=nblk>>3, r=nblk&7;
  int xcd=orig&7, off=orig>>3;
  int wg=(xcd<r? xcd*(q+1) : r*(q+1)+(xcd-r)*q)+off;
  int by=wg/5, bx=wg-5*by;
  int row0=by*128, col0=bx*128;
  int wr=w>>1, wc=w&1;

  f32x4 zero = {0.f,0.f,0.f,0.f};
  f32x4 acc[4][4];
  #pragma unroll
  for(int i=0;i<4;i++)
    #pragma unroll
    for(int j=0;j<4;j++) acc[i][j]=zero;

  for(int k0=0;k0<KP;k0+=64){
    #pragma unroll
    for(int c=0;c<4;c++){
      int sb=w+4*c;          // fm = sb>>1, ks = sb&1
      int fm=sb>>1, ks=sb&1;
      int acol=k0+ks*32+lg*8;
      size_t aoff=(size_t)(row0+fm*16+l15)*KP + acol;
      size_t boff=(size_t)(col0+fm*16+l15)*KP + acol;
      gload16(Ahi+aoff, &lA[0][sb*512]);
      if constexpr(NT==3) gload16(Alo+aoff, &lA[1][sb*512]);
      gload16(Bhi+boff, &lB[0][sb*512]);
      gload16(Blo+boff, &lB[1][sb*512]);
    }
    __syncthreads();
    #pragma unroll
    for(int ks=0;ks<2;ks++){
      bf16x8 ah[4], bh[4], bl[4];
      #pragma unroll
      for(int i=0;i<4;i++){
        int sbA=(wr*4+i)*2+ks;
        ah[i]=*(const bf16x8*)&lA[0][sbA*512+lane*8];
        int sbB=(wc*4+i)*2+ks;
        bh[i]=*(const bf16x8*)&lB[0][sbB*512+lane*8];
        bl[i]=*(const bf16x8*)&lB[1][sbB*512+lane*8];
      }
      if constexpr(NT==3){
        bf16x8 alv[4];
        #pragma unroll
        for(int i=0;i<4;i++) alv[i]=*(const bf16x8*)&lA[1][((wr*4+i)*2+ks)*512+lane*8];
        #pragma unroll
        for(int i=0;i<4;i++)
          #pragma unroll
          for(int j=0;j<4;j++){
            acc[i][j]=__builtin_amdgcn_mfma_f32_16x16x32_bf16(ah[i], bh[j],acc[i][j],0,0,0);
            acc[i][j]=__builtin_amdgcn_mfma_f32_16x16x32_bf16(alv[i],bh[j],acc[i][j],0,0,0);
            acc[i][j]=__builtin_amdgcn_mfma_f32_16x16x32_bf16(ah[i], bl[j],acc[i][j],0,0,0);
          }
      }else{
        #pragma unroll
        for(int i=0;i<4;i++)
          #pragma unroll
          for(int j=0;j<4;j++){
            acc[i][j]=__builtin_amdgcn_mfma_f32_16x16x32_bf16(ah[i],bh[j],acc[i][j],0,0,0);
            acc[i][j]=__builtin_amdgcn_mfma_f32_16x16x32_bf16(ah[i],bl[j],acc[i][j],0,0,0);
          }
      }
    }
    __syncthreads();
  }

  // ---- epilogue: hb (permuted bf16) + al/ar for head bx ----
  float asv[4], adv[4];
  #pragma unroll
  for(int j=0;j<4;j++){
    int c=col0+wc*64+j*16+l15;
    asv[j]=asrc[c]; adv[j]=adst[c];
  }
  // hb[n*640 + (c&63)*10 + (c>>6)] ; c&63 = j*16+l15 ; c>>6 = bx*2+wc
  #pragma unroll
  for(int i=0;i<4;i++){
    #pragma unroll
    for(int j=0;j<4;j++){
      #pragma unroll
      for(int rr=0;rr<4;rr++){
        int row=row0+wr*64+i*16+lg*4+rr;
        if(row<M) hb[(size_t)row*HC + (j*16+l15)*10 + bx*2+wc]=f2bf(acc[i][j][rr]);
      }
    }
  }
  // per-row partial dot over this wave's 64 cols, reduce across l15
  float* redAl=(float*)&lA[0][0];       // 128*2 floats
  float* redAr=redAl+256;
  #pragma unroll
  for(int i=0;i<4;i++){
    #pragma unroll
    for(int rr=0;rr<4;rr++){
      float sa=0.f, sd=0.f;
      #pragma unroll
      for(int j=0;j<4;j++){ sa+=acc[i][j][rr]*asv[j]; sd+=acc[i][j][rr]*adv[j]; }
      #pragma unroll
      for(int o=1;o<16;o<<=1){ sa+=__shfl_xor(sa,o,64); sd+=__shfl_xor(sd,o,64); }
      if(l15==0){
        int lr=wr*64+i*16+lg*4+rr;
        redAl[lr*2+wc]=sa; redAr[lr*2+wc]=sd;
      }
    }
  }
  __syncthreads();
  if(tid<128){
    int row=row0+tid;
    if(row<M){
      al[(size_t)row*5+bx]=redAl[tid*2]+redAl[tid*2+1];
      ar[(size_t)row*5+bx]=redAr[tid*2]+redAr[tid*2+1];
    }
  }
}

__global__ void k_ae(const float* __restrict__ eattr, const float* __restrict__ ve,
                     float* __restrict__ ae){
  __shared__ float ves[50];
  if(threadIdx.x<50) ves[threadIdx.x]=ve[threadIdx.x];
  __syncthreads();
  int i=blockIdx.x*blockDim.x+threadIdx.x;
  if(i>=N_EDGESC) return;
  float ev[10];
  #pragma unroll
  for(int k=0;k<10;k++) ev[k]=eattr[i*10+k];
  #pragma unroll
  for(int hh=0;hh<5;hh++){
    float s=0.f;
    #pragma unroll
    for(int k=0;k<10;k++) s+=ev[k]*ves[k*5+hh];
    ae[(size_t)i*5+hh]=s;
  }
}

// fused segment-softmax + aggregation; one wave per node. Gathers bf16 hb rows.
// WBF: write bf16 (next layer GEMM A input). else: write f32 out.
template<bool RELU, bool WBF>
__global__ __launch_bounds__(256) void k_agg(const u16* __restrict__ hb, const int* __restrict__ src,
    const int* __restrict__ rptr, const int* __restrict__ cnt, const int* __restrict__ eidx,
    const float* __restrict__ al, const float* __restrict__ ar, const float* __restrict__ ael,
    const float* __restrict__ ae, const float* __restrict__ bias,
    float* __restrict__ out, u16* __restrict__ ohi){
  int tid=threadIdx.x, lane=tid&63;
  int n=blockIdx.x*4+(tid>>6);
  if(n>=N_NODESC) return;
  float arn[5], m[5], den[5], acc[10];
  #pragma unroll
  for(int hh=0;hh<5;hh++) arn[hh]=ar[n*5+hh];
  #pragma unroll
  for(int hh=0;hh<5;hh++){
    m[hh]=lrelu(al[n*5+hh]+arn[hh]+ael[n*5+hh]);
    den[hh]=1.f;
  }
  {
    const u32* sp=(const u32*)(hb+(size_t)n*HC+lane*10);
    #pragma unroll
    for(int j2=0;j2<5;j2++){
      u32 wv=sp[j2];
      acc[2*j2]  =bflo(wv);
      acc[2*j2+1]=bfhi(wv);
    }
  }
  int beg=rptr[n], deg=cnt[n];
  for(int off0=0; off0<deg; off0+=64){
    int c=min(64,deg-off0);
    bool valid = lane<c;
    int s=0; float p[5];
    #pragma unroll
    for(int hh=0;hh<5;hh++) p[hh]=-1e30f;
    if(valid){
      int e=eidx[beg+off0+lane];
      s=src[e];
      #pragma unroll
      for(int hh=0;hh<5;hh++) p[hh]=lrelu(al[s*5+hh]+arn[hh]+ae[(size_t)e*5+hh]);
    }
    float sc[5];
    #pragma unroll
    for(int hh=0;hh<5;hh++){
      float cm=wred_max(p[hh]);
      float nm=fmaxf(m[hh],cm);
      sc[hh]=__expf(m[hh]-nm);
      den[hh]*=sc[hh];
      float pv = valid? __expf(p[hh]-nm) : 0.f;
      p[hh]=pv;
      den[hh]+=wred_sum(pv);
      m[hh]=nm;
    }
    #pragma unroll
    for(int k=0;k<10;k++) acc[k]*=sc[k>>1];
    for(int j=0;j<c;j++){
      int sj=__shfl(s,j,64);
      float pj[5];
      #pragma unroll
      for(int hh=0;hh<5;hh++) pj[hh]=__shfl(p[hh],j,64);
      const u32* hr=(const u32*)(hb+(size_t)sj*HC+lane*10);
      #pragma unroll
      for(int j2=0;j2<5;j2++){
        u32 wv=hr[j2];
        acc[2*j2]  +=pj[j2]*bflo(wv);
        acc[2*j2+1]+=pj[j2]*bfhi(wv);
      }
    }
  }
  #pragma unroll
  for(int k=0;k<10;k++){
    int ccol=lane+64*k;
    float v=acc[k]/(den[k>>1]+1e-16f)+bias[ccol];
    if(RELU) v=fmaxf(v,0.f);
    if(WBF){
      ohi[(size_t)n*HC+ccol]=f2bf(v);
    }else{
      out[(size_t)n*HC+ccol]=v;
    }
  }
}

// ---------------- pooling + head ----------------

__global__ __launch_bounds__(256) void k_pool(const float* __restrict__ h, const float* __restrict__ wlin,
    const int* __restrict__ batch, float* __restrict__ ysum, float* __restrict__ cntg){
  int tid=threadIdx.x, lane=tid&63;
  int n=blockIdx.x*4+(tid>>6);
  if(n>=N_NODESC) return;
  float s=0.f;
  #pragma unroll
  for(int k=0;k<10;k++){ int c=lane+64*k; s+=h[(size_t)n*HC+c]*wlin[c]; }
  s=wred_sum(s);
  if(lane==0){
    int g=batch[n];
    atomicAdd(&ysum[g],s);
    atomicAdd(&cntg[g],1.f);
  }
}

__global__ void k_final(const float* __restrict__ ysum, const float* __restrict__ cntg,
                        const float* __restrict__ blin, float* __restrict__ out){
  int g=blockIdx.x*blockDim.x+threadIdx.x;
  if(g>=NGRAPH) return;
  out[g]=ysum[g]/fmaxf(cntg[g],1.f)+blin[0];
}

// ---------------- launch ----------------

extern "C" void kernel_launch(void* const* d_in, const int* in_sizes, int n_in,
                              void* d_out, int out_size, void* d_ws, size_t ws_size,
                              hipStream_t stream){
  const float* x     = (const float*)d_in[0];
  const float* eattr = (const float*)d_in[1];
  const float* W[3]    ={(const float*)d_in[2],(const float*)d_in[8],(const float*)d_in[14]};
  const float* We[3]   ={(const float*)d_in[3],(const float*)d_in[9],(const float*)d_in[15]};
  const float* asrc[3] ={(const float*)d_in[4],(const float*)d_in[10],(const float*)d_in[16]};
  const float* adst[3] ={(const float*)d_in[5],(const float*)d_in[11],(const float*)d_in[17]};
  const float* aedge[3]={(const float*)d_in[6],(const float*)d_in[12],(const float*)d_in[18]};
  const float* bias[3] ={(const float*)d_in[7],(const float*)d_in[13],(const float*)d_in[19]};
  const float* Wlin  = (const float*)d_in[20];
  const float* blin  = (const float*)d_in[21];
  const int* eind    = (const int*)d_in[22];
  const int* srcp    = eind;
  const int* dstp    = eind + N_EDGESC;
  const int* batch   = (const int*)d_in[23];
  float* out = (float*)d_out;

  char* ws=(char*)d_ws;
  size_t o=0;
  auto alloc=[&](size_t bytes)->void*{ void* p=ws+o; o=(o+bytes+255)&~(size_t)255; return p; };
  u16* hb   =(u16*)alloc((size_t)N_NODESC*HC*2);           // permuted bf16 h
  float* aggf =(float*)alloc((size_t)N_NODESC*HC*4);       // final layer f32 out
  u16* Ahi =(u16*)alloc((size_t)N_NODESC*HC*2);            // agg bf16 out (next GEMM A)
  u16* Axhi=(u16*)alloc((size_t)N_NODESC*64*2);            // converted x (KP=64)
  u16* Axlo=(u16*)alloc((size_t)N_NODESC*64*2);
  u16* Bthi=(u16*)alloc((size_t)HC*HC*2);                  // transposed weights
  u16* Btlo=(u16*)alloc((size_t)HC*HC*2);
  float* al   =(float*)alloc((size_t)N_NODESC*5*4);
  float* ar   =(float*)alloc((size_t)N_NODESC*5*4);
  float* ael  =(float*)alloc((size_t)N_NODESC*5*4);
  float* ae   =(float*)alloc((size_t)N_EDGESC*5*4);
  float* lattr=(float*)alloc((size_t)N_NODESC*10*4);
  float* ve   =(float*)alloc(64*4);
  float* ysum =(float*)alloc(512*4);
  float* cntg =(float*)alloc(512*4);
  int* cntI   =(int*)alloc((size_t)N_NODESC*4);
  int* rptr   =(int*)alloc((size_t)N_NODESC*4);
  int* pos    =(int*)alloc((size_t)N_NODESC*4);
  int* eidx   =(int*)alloc((size_t)N_EDGESC*4);

  hipMemsetAsync(cntI,0,(size_t)N_NODESC*4,stream);
  hipMemsetAsync(ysum,0,512*4,stream);
  hipMemsetAsync(cntg,0,512*4,stream);

  k_count<<<(N_EDGESC+255)/256,256,0,stream>>>(dstp,cntI);
  k_scan<<<1,1024,0,stream>>>(cntI,rptr,pos);
  k_scatter<<<(N_EDGESC+255)/256,256,0,stream>>>(dstp,pos,eidx);
  k_loop_attr<<<(N_NODESC+3)/4,256,0,stream>>>(eattr,rptr,cntI,eidx,lattr);
  k_conv_x<<<(N_NODESC*64+255)/256,256,0,stream>>>(x,Axhi,Axlo);

  const int NBLK=5*((N_NODESC+127)/128);
  for(int L=0;L<3;L++){
    int KL = (L==0)? 43 : HC;
    int KP = (L==0)? 64 : HC;
    k_ve<<<1,64,0,stream>>>(We[L],aedge[L],ve);
    k_conv_w<<<(HC*KP+255)/256,256,0,stream>>>(W[L],Bthi,Btlo,KL,KP);
    if(L==0)
      k_gemm_fused<3><<<NBLK,256,0,stream>>>(Axhi,Axlo,Bthi,Btlo,asrc[L],adst[L],hb,al,ar,N_NODESC,KP,NBLK);
    else
      k_gemm_fused<2><<<NBLK,256,0,stream>>>(Ahi,(const u16*)nullptr,Bthi,Btlo,asrc[L],adst[L],hb,al,ar,N_NODESC,KP,NBLK);
    k_ael<<<(N_NODESC*5+255)/256,256,0,stream>>>(lattr,ve,ael);
    k_ae<<<(N_EDGESC+255)/256,256,0,stream>>>(eattr,ve,ae);
    if(L<2)
      k_agg<true ,true ><<<(N_NODESC+3)/4,256,0,stream>>>(hb,srcp,rptr,cntI,eidx,al,ar,ael,ae,bias[L],aggf,Ahi);
    else
      k_agg<false,false><<<(N_NODESC+3)/4,256,0,stream>>>(hb,srcp,rptr,cntI,eidx,al,ar,ael,ae,bias[L],aggf,Ahi);
  }
  k_pool<<<(N_NODESC+3)/4,256,0,stream>>>(aggf,Wlin,batch,ysum,cntg);
  k_final<<<2,256,0,stream>>>(ysum,cntg,blin,out);
}